// Round 8
// baseline (3152.182 us; speedup 1.0000x reference)
//
#include <hip/hip_runtime.h>
#include <hip/hip_bf16.h>
#include <math.h>

#define SEQ 70
#define HID 230
#define G3  690
#define EMBD 50
#define DIN 60
#define NTOT 2048
#define NREL 100
#define NBAG 64
#define BAGSZ 32
#define PDIM 5
#define MB 8      // sentences per GRU block
#define KU 10     // k-rows per pipeline block
#define KTOT 290  // DIN + HID unified K stream
#define SROWS 292 // KTOT + 2 pad rows for row-prefetch overrun

// ---------------- prep kernels ----------------

__global__ void k_zero(float* p, long n) {
    long i = (long)blockIdx.x * 256 + threadIdx.x;
    if (i < n) p[i] = 0.f;
}

__global__ void k_embed(const int* __restrict__ sent, const int* __restrict__ p1,
                        const int* __restrict__ p2,  const float* __restrict__ wemb,
                        const float* __restrict__ t1, const float* __restrict__ t2,
                        float* __restrict__ emb) {
    long idx = (long)blockIdx.x * 256 + threadIdx.x;
    long total = (long)NTOT * SEQ * DIN;
    if (idx >= total) return;
    int nt = (int)(idx / DIN);
    int j  = (int)(idx % DIN);
    float v;
    if (j < EMBD)            v = wemb[(long)sent[nt] * EMBD + j];
    else if (j < EMBD + PDIM) v = t1[p1[nt] * PDIM + (j - EMBD)];
    else                      v = t2[p2[nt] * PDIM + (j - EMBD - PDIM)];
    emb[idx] = v;
}

// in[g*K+k] -> out[k*G+g]
__global__ void k_transpose(const float* __restrict__ in, float* __restrict__ out,
                            int G, int K) {
    int idx = blockIdx.x * 256 + threadIdx.x;
    if (idx >= G * K) return;
    int g = idx / K, k = idx % K;
    out[k * G + g] = in[idx];
}

// ---------------- GRU (both directions in one launch) ----------------
// grid = (NTOT/MB)*2 = 512 blocks of 256 threads. blockIdx.x&1 = direction.
// Thread tid < HID owns gates (tid, HID+tid, 2*HID+tid) -> thread-local combine.
// REGISTER BUDGET (the R5-R7 lesson): any launch_bounds whose workgroup needs
// >=2 waves/SIMD resident makes the backend cap VGPRs at 128 -> the ~160-reg
// pipeline spills (~1.9 GB scratch traffic). (256,1) is the only spill-free
// compile (R4: 200 regs, FETCH 37 MB). With MB=8 the kernel needs ~160 regs,
// and the HARDWARE still co-schedules 2 blocks/CU (2 waves/SIMD) whenever
// VGPR <= 256 — so we get R5's TLP with R4's clean register file.
// Unified K stream: wcat rows 0..59 = Wih^T, rows 60..289 = Whh^T.
// s_s rows 0..59 = emb tile (staged per t), rows 60..289 = h state.
// Software pipeline: weight blocks (KU=10 rows) double-buffered (A/B),
// LDS rows depth-2 rotated (ra*/rb*). All register indices compile-time.
// tup must be zeroed beforehand; both directions atomicAdd into it.

#define ROWLD(R0,R1, kk) { const float4* _p = (const float4*)s_s[kk]; \
    R0 = _p[0]; R1 = _p[1]; }

#define FMA4(WR,WZ,WN, Q, B, AR,AZ,AN) \
    AR[B+0]=fmaf(WR,Q.x,AR[B+0]); AZ[B+0]=fmaf(WZ,Q.x,AZ[B+0]); AN[B+0]=fmaf(WN,Q.x,AN[B+0]); \
    AR[B+1]=fmaf(WR,Q.y,AR[B+1]); AZ[B+1]=fmaf(WZ,Q.y,AZ[B+1]); AN[B+1]=fmaf(WN,Q.y,AN[B+1]); \
    AR[B+2]=fmaf(WR,Q.z,AR[B+2]); AZ[B+2]=fmaf(WZ,Q.z,AZ[B+2]); AN[B+2]=fmaf(WN,Q.z,AN[B+2]); \
    AR[B+3]=fmaf(WR,Q.w,AR[B+3]); AZ[B+3]=fmaf(WZ,Q.w,AZ[B+3]); AN[B+3]=fmaf(WN,Q.w,AN[B+3]);

#define FMA8(WR,WZ,WN, AR,AZ,AN, Q0,Q1) \
    FMA4(WR,WZ,WN, Q0, 0, AR,AZ,AN) FMA4(WR,WZ,WN, Q1, 4, AR,AZ,AN)

#define WLOAD(BR,BZ,BN, KB) { _Pragma("unroll") for (int _u = 0; _u < KU; ++_u) { \
    int _kk = ((KB)*KU + _u) * G3; BR[_u]=pr[_kk]; BZ[_u]=pz[_kk]; BN[_u]=pn[_kk]; } }

// two k-steps: compute k=KB*KU+UE (even row regs) then +1 (odd), each followed
// by prefetch of row k+2 into the regs just freed.
#define U2(BR,BZ,BN, KB, UE, AR,AZ,AN) \
    FMA8(BR[UE],BZ[UE],BN[UE], AR,AZ,AN, ra0,ra1); \
    ROWLD(ra0,ra1, (KB)*KU+(UE)+2); \
    FMA8(BR[UE+1],BZ[UE+1],BN[UE+1], AR,AZ,AN, rb0,rb1); \
    ROWLD(rb0,rb1, (KB)*KU+(UE)+3);

#define BLK10(BR,BZ,BN, KB, AR,AZ,AN) \
    U2(BR,BZ,BN, KB, 0, AR,AZ,AN) U2(BR,BZ,BN, KB, 2, AR,AZ,AN) \
    U2(BR,BZ,BN, KB, 4, AR,AZ,AN) U2(BR,BZ,BN, KB, 6, AR,AZ,AN) \
    U2(BR,BZ,BN, KB, 8, AR,AZ,AN)

#define PAIR(KB, AR,AZ,AN) \
    WLOAD(wBr,wBz,wBn, (KB)+1) BLK10(wAr,wAz,wAn, (KB),   AR,AZ,AN) \
    WLOAD(wAr,wAz,wAn, (KB)+2) BLK10(wBr,wBz,wBn, (KB)+1, AR,AZ,AN)

__global__ __launch_bounds__(256, 1) void k_gru(
    const float* __restrict__ emb,
    const float* __restrict__ wcat_f, const float* __restrict__ bih_f, const float* __restrict__ bhh_f,
    const float* __restrict__ wcat_b, const float* __restrict__ bih_b, const float* __restrict__ bhh_b,
    float* __restrict__ tup) {

    const bool rev = blockIdx.x & 1;
    const int  n0  = (blockIdx.x >> 1) * MB;
    const float* wcat = rev ? wcat_b : wcat_f;
    const float* bih  = rev ? bih_b  : bih_f;
    const float* bhh  = rev ? bhh_b  : bhh_f;
    const int tid = threadIdx.x;
    const bool act = tid < HID;

    __shared__ float s_s[SROWS][MB];   // 9344 B: rows 0..59 = e, 60..289 = h

    for (int i = tid; i < SROWS * MB; i += 256) ((float*)s_s)[i] = 0.f;

    float bir = 0.f, biz = 0.f, bin_ = 0.f, bhr = 0.f, bhz = 0.f, bhn = 0.f;
    if (act) {
        bir = bih[tid]; biz = bih[HID + tid]; bin_ = bih[2 * HID + tid];
        bhr = bhh[tid]; bhz = bhh[HID + tid]; bhn = bhh[2 * HID + tid];
    }
    float hprev[MB];
#pragma unroll
    for (int n = 0; n < MB; ++n) hprev[n] = 0.f;

    const float* pr = wcat + tid;            // row k at pr[k*G3]
    const float* pz = wcat + HID + tid;
    const float* pn = wcat + 2 * HID + tid;

    __syncthreads();

    for (int t = 0; t < SEQ; ++t) {
        const int tt = rev ? (SEQ - 1 - t) : t;

        // stage emb tile into s_s rows 0..59
        for (int i = tid; i < DIN * MB; i += 256) {
            int n = i / DIN, k = i - n * DIN;
            s_s[k][n] = emb[((long)(n0 + n) * SEQ + tt) * DIN + k];
        }
        __syncthreads();   // A: e rows staged, h rows published

        float ar[MB], az[MB], an[MB], hr[MB], hz[MB], hn[MB];
        if (act) {
#pragma unroll
            for (int n = 0; n < MB; ++n) {
                ar[n] = bir; az[n] = biz; an[n] = bin_;
                hr[n] = bhr; hz[n] = bhz; hn[n] = bhn;
            }
            float wAr[KU], wAz[KU], wAn[KU], wBr[KU], wBz[KU], wBn[KU];
            float4 ra0, ra1, rb0, rb1;

            // pipeline prologue
            WLOAD(wAr,wAz,wAn, 0)
            ROWLD(ra0,ra1, 0)
            ROWLD(rb0,rb1, 1)

            // input projection: blocks 0..5 (k = 0..59)
#pragma clang loop unroll(disable)
            for (int kb = 0; kb < 6; kb += 2) { PAIR(kb, ar,az,an) }
            // hidden projection: blocks 6..27 (k = 60..279)
#pragma clang loop unroll(disable)
            for (int kb = 6; kb < 28; kb += 2) { PAIR(kb, hr,hz,hn) }
            // epilogue block 28 (k = 280..289), no more weight prefetch
            BLK10(wAr,wAz,wAn, 28, hr,hz,hn)
        }
        __syncthreads();   // B: all waves done reading s_s

        // thread-local gate combine -> new h; publish to LDS + tup
        if (act) {
#pragma unroll
            for (int n = 0; n < MB; ++n) {
                float r  = 1.f / (1.f + expf(-(ar[n] + hr[n])));
                float z  = 1.f / (1.f + expf(-(az[n] + hz[n])));
                float nn = tanhf(an[n] + r * hn[n]);
                float hnew = (1.f - z) * nn + z * hprev[n];
                hprev[n] = hnew;
                s_s[DIN + tid][n] = hnew;
                atomicAdd(&tup[((long)(n0 + n) * SEQ + tt) * HID + tid], hnew);
            }
        }
    }
}

// ---------------- word-level attention ----------------
__global__ __launch_bounds__(256) void k_wordattn(
    const float* __restrict__ tup, const float* __restrict__ attw,
    const float* __restrict__ sen_a, const float* __restrict__ sen_r,
    float* __restrict__ repre, float* __restrict__ sbuf) {
    const int n = blockIdx.x, tid = threadIdx.x;
    __shared__ float tl[SEQ * HID];   // 64400 B
    __shared__ float sc[SEQ];
    __shared__ float red[4];
    for (int i = tid; i < SEQ * HID; i += 256) tl[i] = tup[(long)n * SEQ * HID + i];
    __syncthreads();
    if (tid < SEQ) {
        float s = 0.f;
        for (int h = 0; h < HID; ++h) s += tanhf(tl[tid * HID + h]) * attw[h];
        sc[tid] = s;
    }
    __syncthreads();
    if (tid == 0) {
        float m = sc[0];
        for (int t = 1; t < SEQ; ++t) m = fmaxf(m, sc[t]);
        float ssum = 0.f;
        for (int t = 0; t < SEQ; ++t) { float e = expf(sc[t] - m); sc[t] = e; ssum += e; }
        float inv = 1.f / ssum;
        for (int t = 0; t < SEQ; ++t) sc[t] *= inv;
    }
    __syncthreads();
    float part = 0.f;
    if (tid < HID) {
        float r = 0.f;
        for (int t = 0; t < SEQ; ++t) r = fmaf(sc[t], tl[t * HID + tid], r);
        float rep = tanhf(r);
        repre[(long)n * HID + tid] = rep;
        part = rep * sen_a[tid] * sen_r[tid];
    }
    for (int off = 32; off; off >>= 1) part += __shfl_down(part, off, 64);
    if ((tid & 63) == 0) red[tid >> 6] = part;
    __syncthreads();
    if (tid == 0) sbuf[n] = red[0] + red[1] + red[2] + red[3];
}

// ---------------- bag attention + logits + loss + prob + acc ----------------
__global__ __launch_bounds__(256) void k_bag(
    const float* __restrict__ repre, const float* __restrict__ sbuf,
    const float* __restrict__ rel, const float* __restrict__ sen_d,
    const float* __restrict__ y, float* __restrict__ out, float* __restrict__ bagloss) {
    const int b = blockIdx.x, tid = threadIdx.x;
    __shared__ float al[BAGSZ];
    __shared__ float ss[HID];
    __shared__ float lg[NREL];
    if (tid == 0) {
        float m = -1e30f;
        for (int i = 0; i < BAGSZ; ++i) m = fmaxf(m, sbuf[b * BAGSZ + i]);
        float s = 0.f;
        for (int i = 0; i < BAGSZ; ++i) { float e = expf(sbuf[b * BAGSZ + i] - m); al[i] = e; s += e; }
        float inv = 1.f / s;
        for (int i = 0; i < BAGSZ; ++i) al[i] *= inv;
    }
    __syncthreads();
    if (tid < HID) {
        float acc = 0.f;
        for (int i = 0; i < BAGSZ; ++i)
            acc = fmaf(al[i], repre[(long)(b * BAGSZ + i) * HID + tid], acc);
        ss[tid] = acc;
    }
    __syncthreads();
    if (tid < NREL) {
        float acc = sen_d[tid];
        for (int h = 0; h < HID; ++h) acc = fmaf(ss[h], rel[tid * HID + h], acc);
        lg[tid] = acc;
    }
    __syncthreads();
    if (tid == 0) {
        float m = -1e30f; int am = 0;
        for (int r = 0; r < NREL; ++r) if (lg[r] > m) { m = lg[r]; am = r; }
        float s = 0.f;
        for (int r = 0; r < NREL; ++r) s += expf(lg[r] - m);
        float inv = 1.f / s;
        float ym = -1e30f; int ay = 0;
        for (int r = 0; r < NREL; ++r) { float yy = y[b * NREL + r]; if (yy > ym) { ym = yy; ay = r; } }
        out[1 + b] = (am == ay) ? 1.f : 0.f;
        float loss = 0.f;
        for (int r = 0; r < NREL; ++r) {
            float l = lg[r], yy = y[b * NREL + r];
            loss += fmaxf(l, 0.f) - l * yy + log1pf(expf(-fabsf(l)));
            out[1 + NBAG + b * NREL + r] = expf(l - m) * inv;
        }
        bagloss[b] = loss / NREL;
    }
}

__global__ void k_final(const float* __restrict__ bagloss, float* __restrict__ out) {
    if (blockIdx.x == 0 && threadIdx.x == 0) {
        float s = 0.f;
        for (int i = 0; i < NBAG; ++i) s += bagloss[i];
        out[0] = s;
    }
}

// ---------------- host launcher ----------------
extern "C" void kernel_launch(void* const* d_in, const int* in_sizes, int n_in,
                              void* d_out, int out_size, void* d_ws, size_t ws_size,
                              hipStream_t stream) {
    const int*   sent   = (const int*)d_in[0];
    const int*   pos1   = (const int*)d_in[1];
    const int*   pos2   = (const int*)d_in[2];
    // d_in[3] = total_shape (bag layout is fixed: 64 bags x 32)
    const float* ybatch = (const float*)d_in[4];
    const float* wemb   = (const float*)d_in[5];
    const float* p1tab  = (const float*)d_in[6];
    const float* p2tab  = (const float*)d_in[7];
    const float* Wih_f  = (const float*)d_in[8];
    const float* Whh_f  = (const float*)d_in[9];
    const float* bih_f  = (const float*)d_in[10];
    const float* bhh_f  = (const float*)d_in[11];
    const float* Wih_b  = (const float*)d_in[12];
    const float* Whh_b  = (const float*)d_in[13];
    const float* bih_b  = (const float*)d_in[14];
    const float* bhh_b  = (const float*)d_in[15];
    const float* attw   = (const float*)d_in[16];
    const float* sen_a  = (const float*)d_in[17];
    const float* sen_r  = (const float*)d_in[18];
    const float* rel    = (const float*)d_in[19];
    const float* sen_d  = (const float*)d_in[20];
    float* out = (float*)d_out;

    float* ws = (float*)d_ws;
    size_t off = 0;
    float* emb    = ws + off; off += (size_t)NTOT * SEQ * DIN;   // 8,601,600
    float* wcat_f = ws + off; off += (size_t)SROWS * G3;         // 201,480 (rows 0..59 ih, 60..289 hh)
    float* wcat_b = ws + off; off += (size_t)SROWS * G3;
    float* tup    = ws + off; off += (size_t)NTOT * SEQ * HID;   // 32,998,400
    float* repre  = ws + off; off += (size_t)NTOT * HID;
    float* sbuf   = ws + off; off += (size_t)NTOT;
    float* bagloss= ws + off; off += (size_t)NBAG;

    const long tupN = (long)NTOT * SEQ * HID;
    k_zero<<<(int)((tupN + 255) / 256), 256, 0, stream>>>(tup, tupN);

    const long embN = (long)NTOT * SEQ * DIN;
    k_embed<<<(int)((embN + 255) / 256), 256, 0, stream>>>(sent, pos1, pos2, wemb, p1tab, p2tab, emb);

    // wcat rows 0..59 = Wih^T, rows 60..289 = Whh^T
    k_transpose<<<(G3 * DIN + 255) / 256, 256, 0, stream>>>(Wih_f, wcat_f, G3, DIN);
    k_transpose<<<(G3 * HID + 255) / 256, 256, 0, stream>>>(Whh_f, wcat_f + (size_t)DIN * G3, G3, HID);
    k_transpose<<<(G3 * DIN + 255) / 256, 256, 0, stream>>>(Wih_b, wcat_b, G3, DIN);
    k_transpose<<<(G3 * HID + 255) / 256, 256, 0, stream>>>(Whh_b, wcat_b + (size_t)DIN * G3, G3, HID);

    k_gru<<<(NTOT / MB) * 2, 256, 0, stream>>>(emb,
        wcat_f, bih_f, bhh_f,
        wcat_b, bih_b, bhh_b, tup);

    k_wordattn<<<NTOT, 256, 0, stream>>>(tup, attw, sen_a, sen_r, repre, sbuf);

    k_bag<<<NBAG, 256, 0, stream>>>(repre, sbuf, rel, sen_d, ybatch, out, bagloss);

    k_final<<<1, 64, 0, stream>>>(bagloss, out);
}

// Round 9
// 2574.460 us; speedup vs baseline: 1.2244x; 1.2244x over previous
//
#include <hip/hip_runtime.h>
#include <hip/hip_bf16.h>
#include <math.h>

#define SEQ 70
#define HID 230
#define G3  690
#define EMBD 50
#define DIN 60
#define NTOT 2048
#define NREL 100
#define NBAG 64
#define BAGSZ 32
#define PDIM 5
#define MB 8      // sentences per GRU block
#define KU 10     // k-rows per pipeline block
#define KTOT 290  // DIN + HID unified K stream
#define SROWS 292 // KTOT + 2 pad rows for row-prefetch overrun

// ---------------- prep kernels ----------------

__global__ void k_zero(float* p, long n) {
    long i = (long)blockIdx.x * 256 + threadIdx.x;
    if (i < n) p[i] = 0.f;
}

__global__ void k_embed(const int* __restrict__ sent, const int* __restrict__ p1,
                        const int* __restrict__ p2,  const float* __restrict__ wemb,
                        const float* __restrict__ t1, const float* __restrict__ t2,
                        float* __restrict__ emb) {
    long idx = (long)blockIdx.x * 256 + threadIdx.x;
    long total = (long)NTOT * SEQ * DIN;
    if (idx >= total) return;
    int nt = (int)(idx / DIN);
    int j  = (int)(idx % DIN);
    float v;
    if (j < EMBD)            v = wemb[(long)sent[nt] * EMBD + j];
    else if (j < EMBD + PDIM) v = t1[p1[nt] * PDIM + (j - EMBD)];
    else                      v = t2[p2[nt] * PDIM + (j - EMBD - PDIM)];
    emb[idx] = v;
}

// in[g*K+k] -> out[k*G+g]
__global__ void k_transpose(const float* __restrict__ in, float* __restrict__ out,
                            int G, int K) {
    int idx = blockIdx.x * 256 + threadIdx.x;
    if (idx >= G * K) return;
    int g = idx / K, k = idx % K;
    out[k * G + g] = in[idx];
}

// ---------------- GRU (both directions in one launch) ----------------
// grid = (NTOT/MB)*2 = 512 blocks of 256 threads. blockIdx.x&1 = direction.
// Thread tid < HID owns gates (tid, HID+tid, 2*HID+tid) -> thread-local combine.
// OCCUPANCY LAW (R5/R8 measured): 256-thread blocks co-schedule 2/CU only at
// VGPR <= 128; at 180 the HW runs 1 block/CU (occ 12%) and TLP dies. So this
// version is engineered to FIT 128 without spilling:
//   - rolling single weight buffer (30 regs, was 60): after FMAs consume
//     w[UE] of block kb, the same reg is reloaded with block kb+1 row UE —
//     consume-to-use distance = 10 rows (~480cy), same cover as A/B dbuf.
//     The epilogue wraps the prefetch to block 0 (weights are t-invariant),
//     so there is no per-step weight-prologue stall.
//   - no hprev regs: old h is re-read from the thread's own LDS row.
// Unified K stream: wcat rows 0..59 = Wih^T, rows 60..289 = Whh^T.
// s_s rows 0..59 = emb tile (staged per t), rows 60..289 = h state.
// LDS rows depth-2 rotated (ra*/rb*). All register indices compile-time.
// tup must be zeroed beforehand; both directions atomicAdd into it.

#define ROWLD(R0,R1, kk) { const float4* _p = (const float4*)s_s[kk]; \
    R0 = _p[0]; R1 = _p[1]; }

#define FMA4(WR,WZ,WN, Q, B, AR,AZ,AN) \
    AR[B+0]=fmaf(WR,Q.x,AR[B+0]); AZ[B+0]=fmaf(WZ,Q.x,AZ[B+0]); AN[B+0]=fmaf(WN,Q.x,AN[B+0]); \
    AR[B+1]=fmaf(WR,Q.y,AR[B+1]); AZ[B+1]=fmaf(WZ,Q.y,AZ[B+1]); AN[B+1]=fmaf(WN,Q.y,AN[B+1]); \
    AR[B+2]=fmaf(WR,Q.z,AR[B+2]); AZ[B+2]=fmaf(WZ,Q.z,AZ[B+2]); AN[B+2]=fmaf(WN,Q.z,AN[B+2]); \
    AR[B+3]=fmaf(WR,Q.w,AR[B+3]); AZ[B+3]=fmaf(WZ,Q.w,AZ[B+3]); AN[B+3]=fmaf(WN,Q.w,AN[B+3]);

#define FMA8(WR,WZ,WN, AR,AZ,AN, Q0,Q1) \
    FMA4(WR,WZ,WN, Q0, 0, AR,AZ,AN) FMA4(WR,WZ,WN, Q1, 4, AR,AZ,AN)

// two k-steps with rolling weight prefetch: consume w[UE] for block KB, then
// reload the SAME slot with block KB+1 row UE (distance 10 rows ~ 480cy).
#define U2R(KB, UE, AR,AZ,AN) \
    FMA8(wR[UE],wZ[UE],wN[UE], AR,AZ,AN, ra0,ra1); \
    ROWLD(ra0,ra1, (KB)*KU+(UE)+2); \
    { int _kk = (((KB)+1)*KU + (UE)) * G3; wR[UE]=pr[_kk]; wZ[UE]=pz[_kk]; wN[UE]=pn[_kk]; } \
    FMA8(wR[UE+1],wZ[UE+1],wN[UE+1], AR,AZ,AN, rb0,rb1); \
    ROWLD(rb0,rb1, (KB)*KU+(UE)+3); \
    { int _kk = (((KB)+1)*KU + (UE)+1) * G3; wR[UE+1]=pr[_kk]; wZ[UE+1]=pz[_kk]; wN[UE+1]=pn[_kk]; }

// epilogue variant: wrap the weight prefetch to block 0 (for next timestep)
#define U2W(KB, UE, AR,AZ,AN) \
    FMA8(wR[UE],wZ[UE],wN[UE], AR,AZ,AN, ra0,ra1); \
    ROWLD(ra0,ra1, (KB)*KU+(UE)+2); \
    { int _kk = (UE) * G3; wR[UE]=pr[_kk]; wZ[UE]=pz[_kk]; wN[UE]=pn[_kk]; } \
    FMA8(wR[UE+1],wZ[UE+1],wN[UE+1], AR,AZ,AN, rb0,rb1); \
    ROWLD(rb0,rb1, (KB)*KU+(UE)+3); \
    { int _kk = ((UE)+1) * G3; wR[UE+1]=pr[_kk]; wZ[UE+1]=pz[_kk]; wN[UE+1]=pn[_kk]; }

#define BLK10R(KB, AR,AZ,AN) \
    U2R(KB, 0, AR,AZ,AN) U2R(KB, 2, AR,AZ,AN) U2R(KB, 4, AR,AZ,AN) \
    U2R(KB, 6, AR,AZ,AN) U2R(KB, 8, AR,AZ,AN)

#define BLK10W(KB, AR,AZ,AN) \
    U2W(KB, 0, AR,AZ,AN) U2W(KB, 2, AR,AZ,AN) U2W(KB, 4, AR,AZ,AN) \
    U2W(KB, 6, AR,AZ,AN) U2W(KB, 8, AR,AZ,AN)

__global__ __launch_bounds__(256, 2) void k_gru(
    const float* __restrict__ emb,
    const float* __restrict__ wcat_f, const float* __restrict__ bih_f, const float* __restrict__ bhh_f,
    const float* __restrict__ wcat_b, const float* __restrict__ bih_b, const float* __restrict__ bhh_b,
    float* __restrict__ tup) {

    const bool rev = blockIdx.x & 1;
    const int  n0  = (blockIdx.x >> 1) * MB;
    const float* wcat = rev ? wcat_b : wcat_f;
    const float* bih  = rev ? bih_b  : bih_f;
    const float* bhh  = rev ? bhh_b  : bhh_f;
    const int tid = threadIdx.x;
    const bool act = tid < HID;

    __shared__ float s_s[SROWS][MB];   // 9344 B: rows 0..59 = e, 60..289 = h

    for (int i = tid; i < SROWS * MB; i += 256) ((float*)s_s)[i] = 0.f;

    float bir = 0.f, biz = 0.f, bin_ = 0.f, bhr = 0.f, bhz = 0.f, bhn = 0.f;
    if (act) {
        bir = bih[tid]; biz = bih[HID + tid]; bin_ = bih[2 * HID + tid];
        bhr = bhh[tid]; bhz = bhh[HID + tid]; bhn = bhh[2 * HID + tid];
    }

    const float* pr = wcat + tid;            // row k at pr[k*G3]
    const float* pz = wcat + HID + tid;
    const float* pn = wcat + 2 * HID + tid;

    // rolling weight buffer: preload block 0 once; steady-state refills happen
    // inside U2R/U2W with 10-row lead. Weights are t-invariant.
    float wR[KU], wZ[KU], wN[KU];
    if (act) {
#pragma unroll
        for (int u = 0; u < KU; ++u) {
            int kk = u * G3; wR[u] = pr[kk]; wZ[u] = pz[kk]; wN[u] = pn[kk];
        }
    }

    __syncthreads();

    for (int t = 0; t < SEQ; ++t) {
        const int tt = rev ? (SEQ - 1 - t) : t;

        // stage emb tile into s_s rows 0..59
        for (int i = tid; i < DIN * MB; i += 256) {
            int n = i / DIN, k = i - n * DIN;
            s_s[k][n] = emb[((long)(n0 + n) * SEQ + tt) * DIN + k];
        }
        __syncthreads();   // A: e rows staged, h rows published

        float ar[MB], az[MB], an[MB], hr[MB], hz[MB], hn[MB];
        if (act) {
#pragma unroll
            for (int n = 0; n < MB; ++n) {
                ar[n] = bir; az[n] = biz; an[n] = bin_;
                hr[n] = bhr; hz[n] = bhz; hn[n] = bhn;
            }
            float4 ra0, ra1, rb0, rb1;
            ROWLD(ra0,ra1, 0)
            ROWLD(rb0,rb1, 1)

            // input projection: blocks 0..5 (k = 0..59)
#pragma clang loop unroll(disable)
            for (int kb = 0; kb < 6; ++kb) { BLK10R(kb, ar,az,an) }
            // hidden projection: blocks 6..27 (k = 60..279)
#pragma clang loop unroll(disable)
            for (int kb = 6; kb < 28; ++kb) { BLK10R(kb, hr,hz,hn) }
            // epilogue block 28 (k = 280..289), wraps weight prefetch to block 0
            BLK10W(28, hr,hz,hn)
        }
        __syncthreads();   // B: all waves done reading s_s

        // thread-local gate combine -> new h; publish to LDS + tup
        if (act) {
#pragma unroll
            for (int n = 0; n < MB; ++n) {
                float r  = 1.f / (1.f + expf(-(ar[n] + hr[n])));
                float z  = 1.f / (1.f + expf(-(az[n] + hz[n])));
                float nn = tanhf(an[n] + r * hn[n]);
                float hold = s_s[DIN + tid][n];
                float hnew = (1.f - z) * nn + z * hold;
                s_s[DIN + tid][n] = hnew;
                atomicAdd(&tup[((long)(n0 + n) * SEQ + tt) * HID + tid], hnew);
            }
        }
    }
}

// ---------------- word-level attention ----------------
__global__ __launch_bounds__(256) void k_wordattn(
    const float* __restrict__ tup, const float* __restrict__ attw,
    const float* __restrict__ sen_a, const float* __restrict__ sen_r,
    float* __restrict__ repre, float* __restrict__ sbuf) {
    const int n = blockIdx.x, tid = threadIdx.x;
    __shared__ float tl[SEQ * HID];   // 64400 B
    __shared__ float sc[SEQ];
    __shared__ float red[4];
    for (int i = tid; i < SEQ * HID; i += 256) tl[i] = tup[(long)n * SEQ * HID + i];
    __syncthreads();
    if (tid < SEQ) {
        float s = 0.f;
        for (int h = 0; h < HID; ++h) s += tanhf(tl[tid * HID + h]) * attw[h];
        sc[tid] = s;
    }
    __syncthreads();
    if (tid == 0) {
        float m = sc[0];
        for (int t = 1; t < SEQ; ++t) m = fmaxf(m, sc[t]);
        float ssum = 0.f;
        for (int t = 0; t < SEQ; ++t) { float e = expf(sc[t] - m); sc[t] = e; ssum += e; }
        float inv = 1.f / ssum;
        for (int t = 0; t < SEQ; ++t) sc[t] *= inv;
    }
    __syncthreads();
    float part = 0.f;
    if (tid < HID) {
        float r = 0.f;
        for (int t = 0; t < SEQ; ++t) r = fmaf(sc[t], tl[t * HID + tid], r);
        float rep = tanhf(r);
        repre[(long)n * HID + tid] = rep;
        part = rep * sen_a[tid] * sen_r[tid];
    }
    for (int off = 32; off; off >>= 1) part += __shfl_down(part, off, 64);
    if ((tid & 63) == 0) red[tid >> 6] = part;
    __syncthreads();
    if (tid == 0) sbuf[n] = red[0] + red[1] + red[2] + red[3];
}

// ---------------- bag attention + logits + loss + prob + acc ----------------
__global__ __launch_bounds__(256) void k_bag(
    const float* __restrict__ repre, const float* __restrict__ sbuf,
    const float* __restrict__ rel, const float* __restrict__ sen_d,
    const float* __restrict__ y, float* __restrict__ out, float* __restrict__ bagloss) {
    const int b = blockIdx.x, tid = threadIdx.x;
    __shared__ float al[BAGSZ];
    __shared__ float ss[HID];
    __shared__ float lg[NREL];
    if (tid == 0) {
        float m = -1e30f;
        for (int i = 0; i < BAGSZ; ++i) m = fmaxf(m, sbuf[b * BAGSZ + i]);
        float s = 0.f;
        for (int i = 0; i < BAGSZ; ++i) { float e = expf(sbuf[b * BAGSZ + i] - m); al[i] = e; s += e; }
        float inv = 1.f / s;
        for (int i = 0; i < BAGSZ; ++i) al[i] *= inv;
    }
    __syncthreads();
    if (tid < HID) {
        float acc = 0.f;
        for (int i = 0; i < BAGSZ; ++i)
            acc = fmaf(al[i], repre[(long)(b * BAGSZ + i) * HID + tid], acc);
        ss[tid] = acc;
    }
    __syncthreads();
    if (tid < NREL) {
        float acc = sen_d[tid];
        for (int h = 0; h < HID; ++h) acc = fmaf(ss[h], rel[tid * HID + h], acc);
        lg[tid] = acc;
    }
    __syncthreads();
    if (tid == 0) {
        float m = -1e30f; int am = 0;
        for (int r = 0; r < NREL; ++r) if (lg[r] > m) { m = lg[r]; am = r; }
        float s = 0.f;
        for (int r = 0; r < NREL; ++r) s += expf(lg[r] - m);
        float inv = 1.f / s;
        float ym = -1e30f; int ay = 0;
        for (int r = 0; r < NREL; ++r) { float yy = y[b * NREL + r]; if (yy > ym) { ym = yy; ay = r; } }
        out[1 + b] = (am == ay) ? 1.f : 0.f;
        float loss = 0.f;
        for (int r = 0; r < NREL; ++r) {
            float l = lg[r], yy = y[b * NREL + r];
            loss += fmaxf(l, 0.f) - l * yy + log1pf(expf(-fabsf(l)));
            out[1 + NBAG + b * NREL + r] = expf(l - m) * inv;
        }
        bagloss[b] = loss / NREL;
    }
}

__global__ void k_final(const float* __restrict__ bagloss, float* __restrict__ out) {
    if (blockIdx.x == 0 && threadIdx.x == 0) {
        float s = 0.f;
        for (int i = 0; i < NBAG; ++i) s += bagloss[i];
        out[0] = s;
    }
}

// ---------------- host launcher ----------------
extern "C" void kernel_launch(void* const* d_in, const int* in_sizes, int n_in,
                              void* d_out, int out_size, void* d_ws, size_t ws_size,
                              hipStream_t stream) {
    const int*   sent   = (const int*)d_in[0];
    const int*   pos1   = (const int*)d_in[1];
    const int*   pos2   = (const int*)d_in[2];
    // d_in[3] = total_shape (bag layout is fixed: 64 bags x 32)
    const float* ybatch = (const float*)d_in[4];
    const float* wemb   = (const float*)d_in[5];
    const float* p1tab  = (const float*)d_in[6];
    const float* p2tab  = (const float*)d_in[7];
    const float* Wih_f  = (const float*)d_in[8];
    const float* Whh_f  = (const float*)d_in[9];
    const float* bih_f  = (const float*)d_in[10];
    const float* bhh_f  = (const float*)d_in[11];
    const float* Wih_b  = (const float*)d_in[12];
    const float* Whh_b  = (const float*)d_in[13];
    const float* bih_b  = (const float*)d_in[14];
    const float* bhh_b  = (const float*)d_in[15];
    const float* attw   = (const float*)d_in[16];
    const float* sen_a  = (const float*)d_in[17];
    const float* sen_r  = (const float*)d_in[18];
    const float* rel    = (const float*)d_in[19];
    const float* sen_d  = (const float*)d_in[20];
    float* out = (float*)d_out;

    float* ws = (float*)d_ws;
    size_t off = 0;
    float* emb    = ws + off; off += (size_t)NTOT * SEQ * DIN;   // 8,601,600
    float* wcat_f = ws + off; off += (size_t)SROWS * G3;         // 201,480 (rows 0..59 ih, 60..289 hh)
    float* wcat_b = ws + off; off += (size_t)SROWS * G3;
    float* tup    = ws + off; off += (size_t)NTOT * SEQ * HID;   // 32,998,400
    float* repre  = ws + off; off += (size_t)NTOT * HID;
    float* sbuf   = ws + off; off += (size_t)NTOT;
    float* bagloss= ws + off; off += (size_t)NBAG;

    const long tupN = (long)NTOT * SEQ * HID;
    k_zero<<<(int)((tupN + 255) / 256), 256, 0, stream>>>(tup, tupN);

    const long embN = (long)NTOT * SEQ * DIN;
    k_embed<<<(int)((embN + 255) / 256), 256, 0, stream>>>(sent, pos1, pos2, wemb, p1tab, p2tab, emb);

    // wcat rows 0..59 = Wih^T, rows 60..289 = Whh^T
    k_transpose<<<(G3 * DIN + 255) / 256, 256, 0, stream>>>(Wih_f, wcat_f, G3, DIN);
    k_transpose<<<(G3 * HID + 255) / 256, 256, 0, stream>>>(Whh_f, wcat_f + (size_t)DIN * G3, G3, HID);
    k_transpose<<<(G3 * DIN + 255) / 256, 256, 0, stream>>>(Wih_b, wcat_b, G3, DIN);
    k_transpose<<<(G3 * HID + 255) / 256, 256, 0, stream>>>(Whh_b, wcat_b + (size_t)DIN * G3, G3, HID);

    k_gru<<<(NTOT / MB) * 2, 256, 0, stream>>>(emb,
        wcat_f, bih_f, bhh_f,
        wcat_b, bih_b, bhh_b, tup);

    k_wordattn<<<NTOT, 256, 0, stream>>>(tup, attw, sen_a, sen_r, repre, sbuf);

    k_bag<<<NBAG, 256, 0, stream>>>(repre, sbuf, rel, sen_d, ybatch, out, bagloss);

    k_final<<<1, 64, 0, stream>>>(bagloss, out);
}